// Round 1
// baseline (484.614 us; speedup 1.0000x reference)
//
#include <hip/hip_runtime.h>
#include <hip/hip_bf16.h>

// GlimpseNet on MI355X.
// Shapes: B=128, C=3, H=W=512, P=16, NP=3, HG=256, HL=128, D_IN=2304, OUT=(128,384).
// Structure: k1 (foveate + where-path), k2 (split-K gemm glimpse@w1 -> partials),
// k3 (reduce+relu -> @w3 -> +where -> relu -> out).
// ws usage: glimpse 294912 f + partial 1179648 f + where 49152 f  = ~5.8 MB.

#define B_    128
#define C_    3
#define H_    512
#define W_    512
#define P_    16
#define NP_   3
#define HG    256
#define HL    128
#define DIN   2304
#define HOUT  384   // HG + HL

// gemm1 tiling
#define KS 36   // split-K chunks, 36*64 = 2304
#define BK 64
#define BM 32
#define BN 64

// ---------------------------------------------------------------------------
// k1: blocks [0, 1152): foveate block (b, level, c) -> 16x16 tile of glimpse.
//     blocks [1152, 1280): where-path for batch b (hl = relu(l@w2+b2); where = hl@w4+b4).
// ---------------------------------------------------------------------------
__global__ __launch_bounds__(256) void k1_foveate_where(
    const float* __restrict__ x, const float* __restrict__ l,
    const float* __restrict__ w2, const float* __restrict__ b2,
    const float* __restrict__ w4, const float* __restrict__ b4,
    float* __restrict__ glimpse, float* __restrict__ wherebuf)
{
    __shared__ float ld[64 * 64];   // 16 KiB, reused by both roles
    const int bid = blockIdx.x;
    const int t   = threadIdx.x;

    if (bid < B_ * NP_ * C_) {
        const int b     = bid / (NP_ * C_);
        const int rem   = bid % (NP_ * C_);
        const int level = rem / C_;      // 0,1,2 -> sizes 16,32,64
        const int c     = rem % C_;

        // coords: ((l+1)*512)*0.5, truncated. *512 and *0.5 are exact pow2 scales,
        // so rounding matches the JAX reference bit-for-bit.
        const float l0 = l[b * 2 + 0];
        const float l1 = l[b * 2 + 1];
        int sx = (int)(((l0 + 1.0f) * 512.0f) * 0.5f);   // column start (padded coords)
        int sy = (int)(((l1 + 1.0f) * 512.0f) * 0.5f);   // row start
        sx = min(max(sx, 0), 512);  // dynamic_slice clamp (no-op for valid l, kept for safety)
        sy = min(max(sy, 0), 512);

        const float* xc = x + (size_t)(b * C_ + c) * (H_ * W_);
        const int S   = P_ << level;   // 16 / 32 / 64
        const int pad = S >> 1;
        const int lg  = 4 + level;     // log2(S)
        const int py  = t >> 4;
        const int px  = t & 15;

        float out;
        if (level == 0) {
            const int ry = sy - pad + py;
            const int rx = sx - pad + px;
            out = (ry >= 0 && ry < H_ && rx >= 0 && rx < W_) ? xc[ry * W_ + rx] : 0.0f;
        } else {
            // Stage SxS patch (zero-padded out-of-bounds) into LDS, coalesced rows.
            const int n = S * S;
            for (int f = t; f < n; f += 256) {
                const int r  = f >> lg;
                const int cc = f & (S - 1);
                const int ry = sy - pad + r;
                const int rx = sx - pad + cc;
                ld[f] = (ry >= 0 && ry < H_ && rx >= 0 && rx < W_) ? xc[ry * W_ + rx] : 0.0f;
            }
            __syncthreads();
            float s = 0.0f;
            if (level == 1) {           // 2x2 avg pool over 32x32
                #pragma unroll
                for (int dy = 0; dy < 2; ++dy) {
                    const float2 v = *(const float2*)&ld[(py * 2 + dy) * 32 + px * 2];
                    s += v.x + v.y;
                }
                out = s * 0.25f;
            } else {                    // 4x4 avg pool over 64x64
                #pragma unroll
                for (int dy = 0; dy < 4; ++dy) {
                    const float4 v = *(const float4*)&ld[(py * 4 + dy) * 64 + px * 4];
                    s += v.x + v.y + v.z + v.w;
                }
                out = s * 0.0625f;
            }
        }
        // glimpse layout: [b][ (level*C + c)*256 + py*16 + px ]
        glimpse[(size_t)b * DIN + (level * C_ + c) * 256 + t] = out;
    } else {
        // where-path for batch b
        const int b = bid - B_ * NP_ * C_;
        const float l0 = l[b * 2 + 0];
        const float l1 = l[b * 2 + 1];
        if (t < HL) {
            const float v = l0 * w2[t] + l1 * w2[HL + t] + b2[t];
            ld[t] = fmaxf(v, 0.0f);     // hl
        }
        __syncthreads();
        for (int j = t; j < HOUT; j += 256) {
            float acc = b4[j];
            #pragma unroll 8
            for (int i = 0; i < HL; ++i) acc += ld[i] * w4[i * HOUT + j];
            wherebuf[b * HOUT + j] = acc;   // no relu here (relu is after what+where)
        }
    }
}

// ---------------------------------------------------------------------------
// k2: split-K GEMM  partial[ks][b][j] = glimpse[b, k0:k0+64] @ w1[k0:k0+64, j]
// grid = 16 (4 bt x 4 jt) * 36 ks = 576 blocks, 256 threads, 32x64 tile.
// ---------------------------------------------------------------------------
__global__ __launch_bounds__(256) void k2_gemm1(
    const float* __restrict__ glimpse, const float* __restrict__ w1,
    float* __restrict__ partial)
{
    __shared__ float As[BM][BK + 4];   // stride 68: breaks 4-way bank aliasing on A reads
    __shared__ float Bs[BK][BN];

    const int bid = blockIdx.x;
    const int ks  = bid % KS;
    const int jb  = bid / KS;
    const int jt  = jb & 3;
    const int bt  = jb >> 2;
    const int t   = threadIdx.x;
    const int k0  = ks * BK;

    // Load A tile: 32x64 floats = 512 float4, 2 per thread (coalesced, 16B aligned).
    {
        int f = t;
        int row = f >> 4, c4 = f & 15;
        float4 v = *(const float4*)&glimpse[(size_t)(bt * BM + row) * DIN + k0 + c4 * 4];
        *(float4*)&As[row][c4 * 4] = v;
        f = t + 256;
        row = f >> 4; c4 = f & 15;
        float4 v2 = *(const float4*)&glimpse[(size_t)(bt * BM + row) * DIN + k0 + c4 * 4];
        *(float4*)&As[row][c4 * 4] = v2;
    }
    // Load B tile: 64x64 floats = 1024 float4, 4 per thread.
    #pragma unroll
    for (int i = 0; i < 4; ++i) {
        const int f  = t + 256 * i;
        const int kr = f >> 4, c4 = f & 15;
        float4 v = *(const float4*)&w1[(size_t)(k0 + kr) * HG + jt * BN + c4 * 4];
        *(float4*)&Bs[kr][c4 * 4] = v;
    }
    __syncthreads();

    const int tx = t & 15;    // column group (4 cols)
    const int ty = t >> 4;    // rows ty and ty+16
    float4 acc0 = {0.f, 0.f, 0.f, 0.f};
    float4 acc1 = {0.f, 0.f, 0.f, 0.f};
    #pragma unroll 8
    for (int k = 0; k < BK; ++k) {
        const float a0 = As[ty][k];
        const float a1 = As[ty + 16][k];
        const float4 bv = *(const float4*)&Bs[k][tx * 4];
        acc0.x += a0 * bv.x; acc0.y += a0 * bv.y; acc0.z += a0 * bv.z; acc0.w += a0 * bv.w;
        acc1.x += a1 * bv.x; acc1.y += a1 * bv.y; acc1.z += a1 * bv.z; acc1.w += a1 * bv.w;
    }
    float* p0 = &partial[((size_t)(ks * B_ + bt * BM + ty)) * HG + jt * BN + tx * 4];
    *(float4*)p0 = acc0;
    float* p1 = &partial[((size_t)(ks * B_ + bt * BM + ty + 16)) * HG + jt * BN + tx * 4];
    *(float4*)p1 = acc1;
}

// ---------------------------------------------------------------------------
// k3: per batch row b: hs = relu(b1 + sum_s partial[s][b][:]) in LDS;
//     out[b][j] = relu( b3[j] + where[b][j] + sum_i hs[i]*w3[i][j] ).
// grid = 128 blocks x 384 threads.
// ---------------------------------------------------------------------------
__global__ __launch_bounds__(384) void k3_out(
    const float* __restrict__ partial, const float* __restrict__ b1,
    const float* __restrict__ w3, const float* __restrict__ b3,
    const float* __restrict__ wherebuf, float* __restrict__ out)
{
    __shared__ float hs[HG];
    const int b = blockIdx.x;
    const int t = threadIdx.x;

    if (t < HG) {
        float acc = b1[t];
        #pragma unroll 4
        for (int s = 0; s < KS; ++s)
            acc += partial[((size_t)(s * B_ + b)) * HG + t];
        hs[t] = fmaxf(acc, 0.0f);
    }
    __syncthreads();

    float acc = b3[t] + wherebuf[b * HOUT + t];
    #pragma unroll 8
    for (int i = 0; i < HG; ++i)
        acc += hs[i] * w3[i * HOUT + t];    // hs broadcast (free), w3 coalesced over t
    out[(size_t)b * HOUT + t] = fmaxf(acc, 0.0f);
}

// ---------------------------------------------------------------------------
extern "C" void kernel_launch(void* const* d_in, const int* in_sizes, int n_in,
                              void* d_out, int out_size, void* d_ws, size_t ws_size,
                              hipStream_t stream) {
    const float* x_t = (const float*)d_in[0];
    const float* l_t = (const float*)d_in[1];
    const float* w1  = (const float*)d_in[2];
    const float* b1  = (const float*)d_in[3];
    const float* w2  = (const float*)d_in[4];
    const float* b2  = (const float*)d_in[5];
    const float* w3  = (const float*)d_in[6];
    const float* b3  = (const float*)d_in[7];
    const float* w4  = (const float*)d_in[8];
    const float* b4  = (const float*)d_in[9];
    float* out = (float*)d_out;

    float* ws       = (float*)d_ws;
    float* glimpse  = ws;                                  // 128*2304
    float* partial  = glimpse + (size_t)B_ * DIN;          // 36*128*256
    float* wherebuf = partial + (size_t)KS * B_ * HG;      // 128*384

    k1_foveate_where<<<B_ * NP_ * C_ + B_, 256, 0, stream>>>(
        x_t, l_t, w2, b2, w4, b4, glimpse, wherebuf);
    k2_gemm1<<<16 * KS, 256, 0, stream>>>(glimpse, w1, partial);
    k3_out<<<B_, 384, 0, stream>>>(partial, b1, w3, b3, wherebuf, out);
}

// Round 2
// 482.959 us; speedup vs baseline: 1.0034x; 1.0034x over previous
//
#include <hip/hip_runtime.h>
#include <hip/hip_bf16.h>

// GlimpseNet on MI355X.
// Shapes: B=128, C=3, H=W=512, P=16, NP=3, HG=256, HL=128, D_IN=2304, OUT=(128,384).
// R1 structure:
//   k1 (384 blocks): one block per (b,c) stages the 64x64 patch in LDS once and
//      emits all 3 foveation levels (16^2/32^2/64^2 are concentric -> sub-windows).
//   k2 (576 blocks): split-K fp32 GEMM glimpse@w1 -> 36 partials.
//   k3 (128 blocks): reduce partials + b1 + relu -> hs; hl = relu(l@w2+b2);
//      out = relu(hs@w3 + hl@w4 + b3 + b4).   (where-path fused here)
// ws: glimpse 128*2304 f + partial 36*128*256 f = ~5.9 MB.

#define B_    128
#define C_    3
#define H_    512
#define W_    512
#define P_    16
#define HG    256
#define HL    128
#define DIN   2304
#define HOUT  384   // HG + HL

// gemm1 tiling
#define KS 36   // split-K chunks, 36*64 = 2304
#define BK 64
#define BM 32
#define BN 64

// ---------------------------------------------------------------------------
// k1: one block per (b,c). Stage 64x64 zero-padded patch centered at coords,
// then derive all three levels from LDS:
//   level0 = center 16x16 (rows/cols 24..39)
//   level1 = 2x2 avg-pool of center 32x32 (rows/cols 16..47)
//   level2 = 4x4 avg-pool of the full 64x64
// Sub-window equivalence with the reference holds because dynamic_slice starts
// are in [0,512] (never clamped) and zero-padding is center-consistent.
// ---------------------------------------------------------------------------
__global__ __launch_bounds__(256) void k1_foveate(
    const float* __restrict__ x, const float* __restrict__ l,
    float* __restrict__ glimpse)
{
    __shared__ float ld[64 * 64];   // 16 KiB
    const int bid = blockIdx.x;     // b*C + c
    const int b = bid / C_;
    const int c = bid % C_;
    const int t = threadIdx.x;

    // coords: trunc(0.5*((l+1)*512)) — exact pow2 scales, matches JAX bitwise.
    const float l0 = l[b * 2 + 0];
    const float l1 = l[b * 2 + 1];
    const int sx = (int)(((l0 + 1.0f) * 512.0f) * 0.5f);
    const int sy = (int)(((l1 + 1.0f) * 512.0f) * 0.5f);

    const float* xc = x + (size_t)(b * C_ + c) * (H_ * W_);

    // Stage 64x64 patch: rows sy-32..sy+31, cols sx-32..sx+31, zero-padded.
    for (int f = t; f < 64 * 64; f += 256) {
        const int r  = f >> 6;
        const int cc = f & 63;
        const int ry = sy - 32 + r;
        const int rx = sx - 32 + cc;
        ld[f] = (ry >= 0 && ry < H_ && rx >= 0 && rx < W_) ? xc[ry * W_ + rx] : 0.0f;
    }
    __syncthreads();

    const int py = t >> 4;
    const int px = t & 15;

    // level 0: direct center read
    const float v0 = ld[(24 + py) * 64 + 24 + px];

    // level 1: 2x2 pool of center 32x32
    float s1 = 0.0f;
    #pragma unroll
    for (int dy = 0; dy < 2; ++dy) {
        const float2 v = *(const float2*)&ld[(16 + 2 * py + dy) * 64 + 16 + 2 * px];
        s1 += v.x + v.y;
    }

    // level 2: 4x4 pool of full 64x64
    float s2 = 0.0f;
    #pragma unroll
    for (int dy = 0; dy < 4; ++dy) {
        const float4 v = *(const float4*)&ld[(py * 4 + dy) * 64 + px * 4];
        s2 += v.x + v.y + v.z + v.w;
    }

    float* g = glimpse + (size_t)b * DIN;
    g[(0 * C_ + c) * 256 + t] = v0;
    g[(1 * C_ + c) * 256 + t] = s1 * 0.25f;
    g[(2 * C_ + c) * 256 + t] = s2 * 0.0625f;
}

// ---------------------------------------------------------------------------
// k2: split-K GEMM  partial[ks][b][j] = glimpse[b, k0:k0+64] @ w1[k0:k0+64, j]
// grid = 16 (4 bt x 4 jt) * 36 ks = 576 blocks, 256 threads, 32x64 tile.
// ---------------------------------------------------------------------------
__global__ __launch_bounds__(256) void k2_gemm1(
    const float* __restrict__ glimpse, const float* __restrict__ w1,
    float* __restrict__ partial)
{
    __shared__ float As[BM][BK + 4];   // stride 68: 2-way max bank aliasing (free)
    __shared__ float Bs[BK][BN];

    const int bid = blockIdx.x;
    const int ks  = bid % KS;
    const int jb  = bid / KS;
    const int jt  = jb & 3;
    const int bt  = jb >> 2;
    const int t   = threadIdx.x;
    const int k0  = ks * BK;

    // A tile: 32x64 floats = 512 float4, 2 per thread.
    {
        int f = t;
        int row = f >> 4, c4 = f & 15;
        float4 v = *(const float4*)&glimpse[(size_t)(bt * BM + row) * DIN + k0 + c4 * 4];
        *(float4*)&As[row][c4 * 4] = v;
        f = t + 256;
        row = f >> 4; c4 = f & 15;
        float4 v2 = *(const float4*)&glimpse[(size_t)(bt * BM + row) * DIN + k0 + c4 * 4];
        *(float4*)&As[row][c4 * 4] = v2;
    }
    // B tile: 64x64 floats = 1024 float4, 4 per thread.
    #pragma unroll
    for (int i = 0; i < 4; ++i) {
        const int f  = t + 256 * i;
        const int kr = f >> 4, c4 = f & 15;
        float4 v = *(const float4*)&w1[(size_t)(k0 + kr) * HG + jt * BN + c4 * 4];
        *(float4*)&Bs[kr][c4 * 4] = v;
    }
    __syncthreads();

    const int tx = t & 15;    // column group (4 cols)
    const int ty = t >> 4;    // rows ty and ty+16
    float4 acc0 = {0.f, 0.f, 0.f, 0.f};
    float4 acc1 = {0.f, 0.f, 0.f, 0.f};
    #pragma unroll 8
    for (int k = 0; k < BK; ++k) {
        const float a0 = As[ty][k];
        const float a1 = As[ty + 16][k];
        const float4 bv = *(const float4*)&Bs[k][tx * 4];
        acc0.x += a0 * bv.x; acc0.y += a0 * bv.y; acc0.z += a0 * bv.z; acc0.w += a0 * bv.w;
        acc1.x += a1 * bv.x; acc1.y += a1 * bv.y; acc1.z += a1 * bv.z; acc1.w += a1 * bv.w;
    }
    float* p0 = &partial[((size_t)(ks * B_ + bt * BM + ty)) * HG + jt * BN + tx * 4];
    *(float4*)p0 = acc0;
    float* p1 = &partial[((size_t)(ks * B_ + bt * BM + ty + 16)) * HG + jt * BN + tx * 4];
    *(float4*)p1 = acc1;
}

// ---------------------------------------------------------------------------
// k3: per batch row b:
//   hs = relu(b1 + sum_s partial[s][b][:])      (256 entries, LDS)
//   hl = relu(l[b]@w2 + b2)                     (128 entries, LDS)
//   out[b][j] = relu( b3[j] + b4[j] + hs@w3[:,j] + hl@w4[:,j] )
// grid = 128 blocks x 384 threads.
// ---------------------------------------------------------------------------
__global__ __launch_bounds__(384) void k3_out(
    const float* __restrict__ partial, const float* __restrict__ b1,
    const float* __restrict__ w3, const float* __restrict__ b3,
    const float* __restrict__ l,  const float* __restrict__ w2,
    const float* __restrict__ b2, const float* __restrict__ w4,
    const float* __restrict__ b4, float* __restrict__ out)
{
    __shared__ float hs[HG];
    __shared__ float hl[HL];
    const int b = blockIdx.x;
    const int t = threadIdx.x;

    if (t < HG) {
        // 36 partials with 4 independent accumulators -> pipelined loads.
        float a0 = 0.f, a1 = 0.f, a2 = 0.f, a3 = 0.f;
        #pragma unroll
        for (int s = 0; s < KS; s += 4) {
            a0 += partial[((size_t)((s + 0) * B_ + b)) * HG + t];
            a1 += partial[((size_t)((s + 1) * B_ + b)) * HG + t];
            a2 += partial[((size_t)((s + 2) * B_ + b)) * HG + t];
            a3 += partial[((size_t)((s + 3) * B_ + b)) * HG + t];
        }
        hs[t] = fmaxf((a0 + a1) + (a2 + a3) + b1[t], 0.0f);
    } else if (t < HG + HL) {
        const int j = t - HG;
        const float l0 = l[b * 2 + 0];
        const float l1 = l[b * 2 + 1];
        hl[j] = fmaxf(l0 * w2[j] + l1 * w2[HL + j] + b2[j], 0.0f);
    }
    __syncthreads();

    float acc = b3[t] + b4[t];
    #pragma unroll 8
    for (int i = 0; i < HG; ++i)
        acc += hs[i] * w3[i * HOUT + t];    // hs broadcast (free), w3 coalesced
    #pragma unroll 8
    for (int i = 0; i < HL; ++i)
        acc += hl[i] * w4[i * HOUT + t];
    out[(size_t)b * HOUT + t] = fmaxf(acc, 0.0f);
}

// ---------------------------------------------------------------------------
extern "C" void kernel_launch(void* const* d_in, const int* in_sizes, int n_in,
                              void* d_out, int out_size, void* d_ws, size_t ws_size,
                              hipStream_t stream) {
    const float* x_t = (const float*)d_in[0];
    const float* l_t = (const float*)d_in[1];
    const float* w1  = (const float*)d_in[2];
    const float* b1  = (const float*)d_in[3];
    const float* w2  = (const float*)d_in[4];
    const float* b2  = (const float*)d_in[5];
    const float* w3  = (const float*)d_in[6];
    const float* b3  = (const float*)d_in[7];
    const float* w4  = (const float*)d_in[8];
    const float* b4  = (const float*)d_in[9];
    float* out = (float*)d_out;

    float* ws      = (float*)d_ws;
    float* glimpse = ws;                               // 128*2304
    float* partial = glimpse + (size_t)B_ * DIN;       // 36*128*256

    k1_foveate<<<B_ * C_, 256, 0, stream>>>(x_t, l_t, glimpse);
    k2_gemm1<<<16 * KS, 256, 0, stream>>>(glimpse, w1, partial);
    k3_out<<<B_, 384, 0, stream>>>(partial, b1, w3, b3, l_t, w2, b2, w4, b4, out);
}